// Round 1
// baseline (331.781 us; speedup 1.0000x reference)
//
#include <hip/hip_runtime.h>

#define EPB     64
#define E_TOTAL 262144
#define NPROBE  100000
#define N_ATOMS 20000

// LDS layout (main): two XOR-swizzled [64][128] bf16 tiles -> 32768 B -> 5 blocks/CU
// swizzle: byte_off ^= (row & 7) << 4  (16B-granular, bijective per row)
#define A2_O   0             // A2 / G region, shorts [0, 8192)
#define F1_O   8192          // F1A region, shorts [8192, 16384); EPI (5120 B) + mpart (1 KB) overlay its head
#define LDS_SH 16384         // shorts -> 32768 B total

// workspace layout (shorts)
#define WS1_O  0             // w_s1^T bf16: 128 x 384 ([n][k])
#define WS2_O  49152         // 128 x 128
#define WF1_O  65536         // 128 x 32
#define WF2_O  69632         // 128 x 128
#define WO1_O  86016         // 64 x 128
#define WT_TOT 94208
#define PQ_O   WT_TOT        // PQ[a][512] bf16: [P | Q0 | Q1 | Q2], 20.5 MB

typedef __attribute__((ext_vector_type(8))) short          short8;
typedef __attribute__((ext_vector_type(8))) unsigned short ushort8;
typedef __attribute__((ext_vector_type(4))) float          floatx4;
typedef __attribute__((ext_vector_type(2))) float          floatx2;

#define MFMA16(a, b, c) __builtin_amdgcn_mfma_f32_16x16x32_bf16((a), (b), (c), 0, 0, 0)

__device__ __forceinline__ short f2bf(float x) {            // RNE (prep only)
    unsigned u = __builtin_bit_cast(unsigned, x);
    u = (u + 0x7FFFu + ((u >> 16) & 1u)) >> 16;
    return (short)(unsigned short)u;
}
__device__ __forceinline__ unsigned pk2(float lo, float hi) {   // {bf16(hi)|bf16(lo)} trunc
    return __builtin_amdgcn_perm(__builtin_bit_cast(unsigned, hi),
                                 __builtin_bit_cast(unsigned, lo), 0x07060302u);
}
__device__ __forceinline__ floatx2 bfpair(unsigned w) {     // packed 2xbf16 -> 2xf32
    floatx2 r;
    r.x = __builtin_bit_cast(float, w << 16);
    r.y = __builtin_bit_cast(float, w & 0xffff0000u);
    return r;
}
__device__ __forceinline__ floatx2 fma2(floatx2 a, floatx2 b, floatx2 c) {
    return __builtin_elementwise_fma(a, b, c);
}
// silu via raw v_rcp (1 ulp) instead of IEEE f32 divide (~10-instr div_scale/div_fmas/div_fixup)
__device__ __forceinline__ float silu_f(float x) {
    return x * __builtin_amdgcn_rcpf(1.0f + __expf(-x));
}

struct F8 { float v[8]; };
__device__ __forceinline__ F8 ld8(const float* __restrict__ p) {
    F8 r;
    const float4 a = *(const float4*)p;
    const float4 b = *(const float4*)(p + 4);
    r.v[0] = a.x; r.v[1] = a.y; r.v[2] = a.z; r.v[3] = a.w;
    r.v[4] = b.x; r.v[5] = b.y; r.v[6] = b.z; r.v[7] = b.w;
    return r;
}

// prep 1: out init + weight transpose -> bf16 [n][k]
__global__ void cfr_prep_w(const float* __restrict__ w_s1, const float* __restrict__ w_s2,
                           const float* __restrict__ w_f1, const float* __restrict__ w_f2,
                           const float* __restrict__ w_o1,
                           const float* __restrict__ fb, float* __restrict__ out,
                           unsigned short* __restrict__ wt) {
    int i = blockIdx.x * 256 + threadIdx.x;
    if (i < NPROBE) out[i] = fb[0];
    if (i < WT_TOT) {
        float v;
        if (i < WS2_O)      { int n = i / 384, k = i - n * 384;          v = w_s1[k * 128 + n]; }
        else if (i < WF1_O) { int j = i - WS2_O, n = j >> 7, k = j & 127; v = w_s2[k * 128 + n]; }
        else if (i < WF2_O) { int j = i - WF1_O, n = j >> 5, k = j & 31;  v = w_f1[k * 128 + n]; }
        else if (i < WO1_O) { int j = i - WF2_O, n = j >> 7, k = j & 127; v = w_f2[k * 128 + n]; }
        else                { int j = i - WO1_O, n = j >> 7, k = j & 127; v = w_o1[k * 64 + n]; }
        wt[i] = (unsigned short)f2bf(v);
    }
}

// prep 2: per-atom P = [S|n]@w_s1[0:256] + b_s1 and Q_d = V_d@w_s1[256:384], bf16.
// One block = 64 atoms. LDS cut to 81920 B (XOR-swizzled, no pad) -> 2 blocks/CU.
__global__ __launch_bounds__(256, 2) void cfr_prep_pq(
    const float* __restrict__ S, const float* __restrict__ V,
    const float* __restrict__ b_s1,
    const unsigned short* __restrict__ wt, unsigned short* __restrict__ pq)
{
    __shared__ __align__(16) unsigned short bufH[64 * 256];   // [S|n], swizzled rows of 512 B
    __shared__ __align__(16) unsigned short bufV[192 * 128];  // rows (d*64 + a_local), 256 B

    const int t    = threadIdx.x;
    const int a0   = blockIdx.x * 64;
    const int wave = t >> 6;
    const int lane = t & 63;
    const int q    = lane >> 4;
    const int c16  = lane & 15;

    // stage
#pragma unroll
    for (int it = 0; it < 4; ++it) {
        int idx = it * 256 + t;
        int al = idx >> 4, f8 = (idx & 15) * 8;
        int a = a0 + al;
        ushort8 sS, sN, s0, s1, s2;
        if (a < N_ATOMS) {
            F8 s  = ld8(S + a * 128 + f8);
            F8 v0 = ld8(V + a * 384 + f8);
            F8 v1 = ld8(V + a * 384 + 128 + f8);
            F8 v2 = ld8(V + a * 384 + 256 + f8);
#pragma unroll
            for (int j = 0; j < 8; ++j) {
                sS[j] = (unsigned short)f2bf(s.v[j]);
                sN[j] = (unsigned short)f2bf(sqrtf(v0.v[j]*v0.v[j] + v1.v[j]*v1.v[j] + v2.v[j]*v2.v[j] + 1e-8f));
                s0[j] = (unsigned short)f2bf(v0.v[j]);
                s1[j] = (unsigned short)f2bf(v1.v[j]);
                s2[j] = (unsigned short)f2bf(v2.v[j]);
            }
        } else {
#pragma unroll
            for (int j = 0; j < 8; ++j) { sS[j]=0; sN[j]=0; s0[j]=0; s1[j]=0; s2[j]=0; }
        }
        const unsigned swH = (unsigned)((al & 7) << 4);
        char* hrow  = (char*)bufH + al * 512;
        char* vbase = (char*)bufV;
        *(ushort8*)(hrow + ((f8 * 2) ^ swH))         = sS;
        *(ushort8*)(hrow + ((256 + f8 * 2) ^ swH))   = sN;
        *(ushort8*)(vbase + al * 256         + ((f8 * 2) ^ swH)) = s0;
        *(ushort8*)(vbase + (64 + al) * 256  + ((f8 * 2) ^ swH)) = s1;
        *(ushort8*)(vbase + (128 + al) * 256 + ((f8 * 2) ^ swH)) = s2;
    }
    __syncthreads();

    const floatx4 zero4 = {0.f, 0.f, 0.f, 0.f};
    const unsigned swr = (unsigned)((c16 & 7) << 4);
    float bs1c[2];
#pragma unroll
    for (int ni = 0; ni < 2; ++ni) bs1c[ni] = b_s1[wave * 32 + ni * 16 + c16];

    // P = [S|n] @ w_s1[0:256]
    {
        floatx4 pacc[4][2];
#pragma unroll
        for (int mi = 0; mi < 4; ++mi) { pacc[mi][0] = zero4; pacc[mi][1] = zero4; }
#pragma unroll
        for (int kk = 0; kk < 8; ++kk) {
            short8 bfr[2], af[4];
#pragma unroll
            for (int ni = 0; ni < 2; ++ni) {
                int n = wave * 32 + ni * 16 + c16;
                bfr[ni] = *(const short8*)&wt[WS1_O + n * 384 + kk * 32 + q * 8];
            }
#pragma unroll
            for (int mi = 0; mi < 4; ++mi) {
                int row = mi * 16 + c16;
                af[mi] = *(const short8*)((const char*)bufH + row * 512 + ((unsigned)(kk * 64 + q * 16) ^ swr));
            }
#pragma unroll
            for (int mi = 0; mi < 4; ++mi)
#pragma unroll
                for (int ni = 0; ni < 2; ++ni)
                    pacc[mi][ni] = MFMA16(af[mi], bfr[ni], pacc[mi][ni]);
        }
#pragma unroll
        for (int mi = 0; mi < 4; ++mi)
#pragma unroll
            for (int r = 0; r < 4; ++r) {
                int a = a0 + mi * 16 + q * 4 + r;
                if (a < N_ATOMS)
#pragma unroll
                    for (int ni = 0; ni < 2; ++ni) {
                        int col = wave * 32 + ni * 16 + c16;
                        pq[a * 512 + col] = (unsigned short)f2bf(pacc[mi][ni][r] + bs1c[ni]);
                    }
            }
    }

    // Q_d = V_d @ w_s1[256:384] (B frags hoisted)
    short8 bq[4][2];
#pragma unroll
    for (int kk = 0; kk < 4; ++kk)
#pragma unroll
        for (int ni = 0; ni < 2; ++ni) {
            int n = wave * 32 + ni * 16 + c16;
            bq[kk][ni] = *(const short8*)&wt[WS1_O + n * 384 + 256 + kk * 32 + q * 8];
        }
#pragma unroll
    for (int d = 0; d < 3; ++d) {
        floatx4 qacc[4][2];
#pragma unroll
        for (int mi = 0; mi < 4; ++mi) { qacc[mi][0] = zero4; qacc[mi][1] = zero4; }
#pragma unroll
        for (int kk = 0; kk < 4; ++kk) {
            short8 af[4];
#pragma unroll
            for (int mi = 0; mi < 4; ++mi) {
                int row = d * 64 + mi * 16 + c16;
                af[mi] = *(const short8*)((const char*)bufV + row * 256 + ((unsigned)(kk * 64 + q * 16) ^ swr));
            }
#pragma unroll
            for (int mi = 0; mi < 4; ++mi)
#pragma unroll
                for (int ni = 0; ni < 2; ++ni)
                    qacc[mi][ni] = MFMA16(af[mi], bq[kk][ni], qacc[mi][ni]);
        }
#pragma unroll
        for (int mi = 0; mi < 4; ++mi)
#pragma unroll
            for (int r = 0; r < 4; ++r) {
                int a = a0 + mi * 16 + q * 4 + r;
                if (a < N_ATOMS)
#pragma unroll
                    for (int ni = 0; ni < 2; ++ni) {
                        int col = wave * 32 + ni * 16 + c16;
                        pq[a * 512 + (1 + d) * 128 + col] = (unsigned short)f2bf(qacc[mi][ni][r]);
                    }
            }
    }
}

__global__ __launch_bounds__(256, 5) void cfr_main(
    const float* __restrict__ diff,
    const int* __restrict__ atom_idx, const int* __restrict__ probe_idx,
    const unsigned short* __restrict__ wt, const unsigned short* __restrict__ pq,
    const float* __restrict__ g_ln, const float* __restrict__ b_ln,
    const float* __restrict__ b_s2, const float* __restrict__ b_f1,
    const float* __restrict__ b_f2, const float* __restrict__ b_o1,
    const float* __restrict__ w_o2, const float* __restrict__ b_o2,
    float* __restrict__ out)
{
    __shared__ __align__(16) unsigned short LDSu[LDS_SH];

    const int t    = threadIdx.x;
    const int e0   = blockIdx.x * EPB;
    const int wave = t >> 6;
    const int lane = t & 63;
    const int q    = lane >> 4;
    const int c16  = lane & 15;
    const floatx4 zero4 = {0.f, 0.f, 0.f, 0.f};

    // ---------- phase 1: U = P + r.Q -> LN -> SiLU -> A2 ; EPI ----------
    {
        const int el = t >> 2;             // local edge 0..63
        const int cc = t & 3;              // 32-col chunk id
        const int eg = e0 + el;
        const int a  = atom_idx[eg];
        float dx = diff[eg * 3 + 0], dy = diff[eg * 3 + 1], dz = diff[eg * 3 + 2];
        float sq   = dx * dx + dy * dy + dz * dz;
        float dist = sqrtf(sq);
        float rinv = rsqrtf(sq + 1e-8f);
        float rx = dx * rinv, ry = dy * rinv, rz = dz * rinv;
        float rv[3] = {rx, ry, rz};

        const uint4* pqr = (const uint4*)(pq + (size_t)a * 512) + cc * 4;
        floatx2 u2[16];
#pragma unroll
        for (int g = 0; g < 4; ++g) {          // P
            uint4 w = pqr[g];
            u2[g * 4 + 0] = bfpair(w.x);
            u2[g * 4 + 1] = bfpair(w.y);
            u2[g * 4 + 2] = bfpair(w.z);
            u2[g * 4 + 3] = bfpair(w.w);
        }
#pragma unroll
        for (int d = 0; d < 3; ++d) {          // + r_d * Q_d
            floatx2 rr2; rr2.x = rv[d]; rr2.y = rv[d];
#pragma unroll
            for (int g = 0; g < 4; ++g) {
                uint4 w = pqr[16 * (d + 1) + g];
                u2[g * 4 + 0] = fma2(bfpair(w.x), rr2, u2[g * 4 + 0]);
                u2[g * 4 + 1] = fma2(bfpair(w.y), rr2, u2[g * 4 + 1]);
                u2[g * 4 + 2] = fma2(bfpair(w.z), rr2, u2[g * 4 + 2]);
                u2[g * 4 + 3] = fma2(bfpair(w.w), rr2, u2[g * 4 + 3]);
            }
        }
        // LayerNorm stats: quad-local (threads t^1, t^2 share this edge)
        floatx2 sv2 = {0.f, 0.f}, qv2 = {0.f, 0.f};
#pragma unroll
        for (int p = 0; p < 16; ++p) {
            sv2 += u2[p];
            qv2 = fma2(u2[p], u2[p], qv2);
        }
        float s  = sv2.x + sv2.y;
        float s2 = qv2.x + qv2.y;
        s  += __shfl_xor(s, 1);  s  += __shfl_xor(s, 2);
        s2 += __shfl_xor(s2, 1); s2 += __shfl_xor(s2, 2);
        float mu = s * (1.f / 128.f);
        float rstd = rsqrtf(s2 * (1.f / 128.f) - mu * mu + 1e-5f);
        floatx2 rstd2; rstd2.x = rstd; rstd2.y = rstd;
        float nmr = -mu * rstd;
        floatx2 nm2; nm2.x = nmr; nm2.y = nmr;
        // LN apply + SiLU -> bf16 pack
        const int c0 = cc * 32;
        const float4* gp = (const float4*)(g_ln + c0);
        const float4* bp = (const float4*)(b_ln + c0);
        unsigned pko[16];
#pragma unroll
        for (int g4 = 0; g4 < 8; ++g4) {
            float4 gg = gp[g4], bb = bp[g4];
            floatx2 g0; g0.x = gg.x; g0.y = gg.y;
            floatx2 g1; g1.x = gg.z; g1.y = gg.w;
            floatx2 b0; b0.x = bb.x; b0.y = bb.y;
            floatx2 b1; b1.x = bb.z; b1.y = bb.w;
            floatx2 t0 = fma2(u2[g4 * 2 + 0], rstd2, nm2);
            floatx2 t1 = fma2(u2[g4 * 2 + 1], rstd2, nm2);
            floatx2 y0 = fma2(t0, g0, b0);
            floatx2 y1 = fma2(t1, g1, b1);
            pko[g4 * 2 + 0] = pk2(silu_f(y0.x), silu_f(y0.y));
            pko[g4 * 2 + 1] = pk2(silu_f(y1.x), silu_f(y1.y));
        }
        const unsigned sw = (unsigned)((el & 7) << 4);
        char* a2b = (char*)LDSu + el * 256;
        *(uint4*)(a2b + (((unsigned)(cc * 64) +  0u) ^ sw)) = make_uint4(pko[0],  pko[1],  pko[2],  pko[3]);
        *(uint4*)(a2b + (((unsigned)(cc * 64) + 16u) ^ sw)) = make_uint4(pko[4],  pko[5],  pko[6],  pko[7]);
        *(uint4*)(a2b + (((unsigned)(cc * 64) + 32u) ^ sw)) = make_uint4(pko[8],  pko[9],  pko[10], pko[11]);
        *(uint4*)(a2b + (((unsigned)(cc * 64) + 48u) ^ sw)) = make_uint4(pko[12], pko[13], pko[14], pko[15]);
        // EPI: 8 RBF cols per thread; v_sin takes revolutions: arg = dist*n/(2*CUTOFF*2) = dist*n*0.125
        float inv = __builtin_amdgcn_rcpf(dist);
        float d8  = dist * 0.125f;
        float nb  = (float)(cc * 8 + 1);
        float svv[8];
#pragma unroll
        for (int j = 0; j < 8; ++j)
            svv[j] = __builtin_amdgcn_sinf(d8 * (nb + (float)j)) * inv;
        *(uint4*)((char*)LDSu + F1_O * 2 + el * 80 + cc * 16) =
            make_uint4(pk2(svv[0], svv[1]), pk2(svv[2], svv[3]), pk2(svv[4], svv[5]), pk2(svv[6], svv[7]));
    }
    __syncthreads();   // A2 + EPI ready

    // ---------- mmf1: F1 = EPI[64x32] @ w_f1 -> silu -> F1A (overlays EPI after barrier) ----------
    {
        short8 ae[4], be[2];
#pragma unroll
        for (int mi = 0; mi < 4; ++mi)
            ae[mi] = *(const short8*)((const char*)LDSu + F1_O * 2 + (mi * 16 + c16) * 80 + q * 16);
#pragma unroll
        for (int ni = 0; ni < 2; ++ni) {
            int n = wave * 32 + ni * 16 + c16;
            be[ni] = *(const short8*)&wt[WF1_O + n * 32 + q * 8];
        }
        __syncthreads();   // all EPI reads complete before F1A overlay writes
        floatx4 facc[4][2];
#pragma unroll
        for (int mi = 0; mi < 4; ++mi)
#pragma unroll
            for (int ni = 0; ni < 2; ++ni)
                facc[mi][ni] = MFMA16(ae[mi], be[ni], zero4);
        float bf1c[2];
#pragma unroll
        for (int ni = 0; ni < 2; ++ni) bf1c[ni] = b_f1[wave * 32 + ni * 16 + c16];
#pragma unroll
        for (int mi = 0; mi < 4; ++mi)
#pragma unroll
            for (int r = 0; r < 4; ++r) {
                int row = mi * 16 + q * 4 + r;
#pragma unroll
                for (int ni = 0; ni < 2; ++ni) {
                    int col = wave * 32 + ni * 16 + c16;
                    float v = facc[mi][ni][r] + bf1c[ni];
                    LDSu[F1_O + row * 128 + (col ^ ((row & 7) << 3))] =
                        (unsigned short)(__builtin_bit_cast(unsigned, silu_f(v)) >> 16);
                }
            }
    }
    __syncthreads();   // F1A ready

    // ---------- mm2: S = A2 @ w_s2 ; mmf2: W = F1A @ w_f2 ; G = S.W -> A2 region ----------
    {
        floatx4 sacc[4][2], wacc[4][2];
#pragma unroll
        for (int mi = 0; mi < 4; ++mi)
#pragma unroll
            for (int ni = 0; ni < 2; ++ni) { sacc[mi][ni] = zero4; wacc[mi][ni] = zero4; }
        const int swr = (c16 & 7) << 3;
#pragma unroll
        for (int kk = 0; kk < 4; ++kk) {
            short8 a2f[4], f1f[4], b2[2], bw[2];
#pragma unroll
            for (int ni = 0; ni < 2; ++ni) {
                int n = wave * 32 + ni * 16 + c16;
                b2[ni] = *(const short8*)&wt[WS2_O + n * 128 + kk * 32 + q * 8];
                bw[ni] = *(const short8*)&wt[WF2_O + n * 128 + kk * 32 + q * 8];
            }
#pragma unroll
            for (int mi = 0; mi < 4; ++mi) {
                int rr = mi * 16 + c16;
                int colsh = (kk * 32 + q * 8) ^ swr;
                a2f[mi] = *(const short8*)&LDSu[A2_O + rr * 128 + colsh];
                f1f[mi] = *(const short8*)&LDSu[F1_O + rr * 128 + colsh];
            }
#pragma unroll
            for (int mi = 0; mi < 4; ++mi)
#pragma unroll
                for (int ni = 0; ni < 2; ++ni) {
                    sacc[mi][ni] = MFMA16(a2f[mi], b2[ni], sacc[mi][ni]);
                    wacc[mi][ni] = MFMA16(f1f[mi], bw[ni], wacc[mi][ni]);
                }
        }
        __syncthreads();   // all reads of A2/F1A complete
        float bs2c[2], bf2c[2];
#pragma unroll
        for (int ni = 0; ni < 2; ++ni) {
            int col = wave * 32 + ni * 16 + c16;
            bs2c[ni] = b_s2[col]; bf2c[ni] = b_f2[col];
        }
#pragma unroll
        for (int mi = 0; mi < 4; ++mi)
#pragma unroll
            for (int r = 0; r < 4; ++r) {
                int row = mi * 16 + q * 4 + r;
#pragma unroll
                for (int ni = 0; ni < 2; ++ni) {
                    int col = wave * 32 + ni * 16 + c16;
                    float g = (sacc[mi][ni][r] + bs2c[ni]) * (wacc[mi][ni][r] + bf2c[ni]);
                    LDSu[A2_O + row * 128 + (col ^ ((row & 7) << 3))] =
                        (unsigned short)(__builtin_bit_cast(unsigned, g) >> 16);
                }
            }
    }
    __syncthreads();   // G ready

    // ---------- head: O1 = G @ w_o1 ; m = silu(O1) @ w_o2 ----------
    {
        const int n2 = wave * 16 + c16;
        const int swr = (c16 & 7) << 3;
        floatx4 oacc[4];
#pragma unroll
        for (int mi = 0; mi < 4; ++mi) oacc[mi] = zero4;
#pragma unroll
        for (int kk = 0; kk < 4; ++kk) {
            short8 bfr = *(const short8*)&wt[WO1_O + n2 * 128 + kk * 32 + q * 8];
#pragma unroll
            for (int mi = 0; mi < 4; ++mi) {
                int rr = mi * 16 + c16;
                short8 af = *(const short8*)&LDSu[A2_O + rr * 128 + ((kk * 32 + q * 8) ^ swr)];
                oacc[mi] = MFMA16(af, bfr, oacc[mi]);
            }
        }
        float bo1c = b_o1[n2], wo2c = w_o2[n2];
        float* mpart = (float*)&LDSu[F1_O];   // overlays F1A (dead after mm2)
#pragma unroll
        for (int mi = 0; mi < 4; ++mi)
#pragma unroll
            for (int r = 0; r < 4; ++r) {
                float s = silu_f(oacc[mi][r] + bo1c) * wo2c;
#pragma unroll
                for (int d = 1; d < 16; d <<= 1) s += __shfl_xor(s, d, 64);
                if (c16 == 0) mpart[(mi * 16 + q * 4 + r) * 4 + wave] = s;
            }
    }
    __syncthreads();

    // ---------- envelope + scatter-add ----------
    if (t < EPB) {
        int eg = e0 + t;
        const float* mpart = (const float*)&LDSu[F1_O];
        float4 mp = *(const float4*)&mpart[t * 4];
        float m = mp.x + mp.y + mp.z + mp.w + b_o2[0];
        float dx = diff[eg * 3 + 0], dy = diff[eg * 3 + 1], dz = diff[eg * 3 + 2];
        float dist = sqrtf(dx * dx + dy * dy + dz * dz);
        float x  = dist * 0.25f;
        float x2 = x * x, x4 = x2 * x2;
        float x5 = x4 * x, x6 = x5 * x, x7 = x6 * x;
        float env = 1.0f - 21.0f * x5 + 35.0f * x6 - 15.0f * x7;
        env = (dist < 4.0f) ? env : 0.0f;
        float mw = m * env;
        if (mw != 0.f) unsafeAtomicAdd(&out[probe_idx[eg]], mw);
    }
}

extern "C" void kernel_launch(void* const* d_in, const int* in_sizes, int n_in,
                              void* d_out, int out_size, void* d_ws, size_t ws_size,
                              hipStream_t stream) {
    const float* diff    = (const float*)d_in[0];
    const float* S_JK    = (const float*)d_in[1];
    const float* V_JK    = (const float*)d_in[2];
    const int*   atom_i  = (const int*)d_in[3];
    const int*   probe_i = (const int*)d_in[4];
    const float* w_s1 = (const float*)d_in[6];
    const float* b_s1 = (const float*)d_in[7];
    const float* g_ln = (const float*)d_in[8];
    const float* b_ln = (const float*)d_in[9];
    const float* w_s2 = (const float*)d_in[10];
    const float* b_s2 = (const float*)d_in[11];
    const float* w_f1 = (const float*)d_in[12];
    const float* b_f1 = (const float*)d_in[13];
    const float* w_f2 = (const float*)d_in[14];
    const float* b_f2 = (const float*)d_in[15];
    const float* w_o1 = (const float*)d_in[16];
    const float* b_o1 = (const float*)d_in[17];
    const float* w_o2 = (const float*)d_in[18];
    const float* b_o2 = (const float*)d_in[19];
    const float* fbias = (const float*)d_in[20];
    float* out = (float*)d_out;

    unsigned short* wt = (unsigned short*)d_ws;
    unsigned short* pqp = wt + PQ_O;   // 20.5 MB

    cfr_prep_w<<<(NPROBE + 255) / 256, 256, 0, stream>>>(w_s1, w_s2, w_f1, w_f2, w_o1,
                                                         fbias, out, wt);
    cfr_prep_pq<<<(N_ATOMS + 63) / 64, 256, 0, stream>>>(S_JK, V_JK, b_s1, wt, pqp);
    cfr_main<<<E_TOTAL / EPB, 256, 0, stream>>>(diff, atom_i, probe_i, wt, pqp,
        g_ln, b_ln, b_s2, b_f1, b_f2, b_o1, w_o2, b_o2, out);
}

// Round 2
// 272.002 us; speedup vs baseline: 1.2198x; 1.2198x over previous
//
#include <hip/hip_runtime.h>

#define EPB     64
#define E_TOTAL 262144
#define NPROBE  100000
#define N_ATOMS 20000

// LDS layout (main): two XOR-swizzled [64][128] bf16 tiles -> 32768 B -> 5 blocks/CU possible
// swizzle: byte_off ^= (row & 7) << 4  (16B-granular, bijective per row)
#define A2_O   0             // A2 / G region, shorts [0, 8192)
#define F1_O   8192          // F1A region, shorts [8192, 16384); EPI (5120 B) + mpart (1 KB) overlay its head
#define LDS_SH 16384         // shorts -> 32768 B total

// workspace layout (shorts)
#define WS1_O  0             // w_s1^T bf16: 128 x 384 ([n][k])
#define WS2_O  49152         // 128 x 128
#define WF1_O  65536         // 128 x 32
#define WF2_O  69632         // 128 x 128
#define WO1_O  86016         // 64 x 128
#define WT_TOT 94208
#define PQ_O   WT_TOT        // PQ[a][512] bf16: [P | Q0 | Q1 | Q2], 20.5 MB

typedef __attribute__((ext_vector_type(8))) short          short8;
typedef __attribute__((ext_vector_type(8))) unsigned short ushort8;
typedef __attribute__((ext_vector_type(4))) float          floatx4;
typedef __attribute__((ext_vector_type(2))) float          floatx2;

#define MFMA16(a, b, c) __builtin_amdgcn_mfma_f32_16x16x32_bf16((a), (b), (c), 0, 0, 0)

__device__ __forceinline__ short f2bf(float x) {            // RNE (prep only)
    unsigned u = __builtin_bit_cast(unsigned, x);
    u = (u + 0x7FFFu + ((u >> 16) & 1u)) >> 16;
    return (short)(unsigned short)u;
}
__device__ __forceinline__ unsigned pk2(float lo, float hi) {   // {bf16(hi)|bf16(lo)} trunc
    return __builtin_amdgcn_perm(__builtin_bit_cast(unsigned, hi),
                                 __builtin_bit_cast(unsigned, lo), 0x07060302u);
}
__device__ __forceinline__ floatx2 bfpair(unsigned w) {     // packed 2xbf16 -> 2xf32
    floatx2 r;
    r.x = __builtin_bit_cast(float, w << 16);
    r.y = __builtin_bit_cast(float, w & 0xffff0000u);
    return r;
}
__device__ __forceinline__ floatx2 fma2(floatx2 a, floatx2 b, floatx2 c) {
    return __builtin_elementwise_fma(a, b, c);
}
// silu via raw v_rcp (1 ulp) instead of IEEE f32 divide (~10-instr div_scale/div_fmas/div_fixup)
__device__ __forceinline__ float silu_f(float x) {
    return x * __builtin_amdgcn_rcpf(1.0f + __expf(-x));
}

struct F8 { float v[8]; };
__device__ __forceinline__ F8 ld8(const float* __restrict__ p) {
    F8 r;
    const float4 a = *(const float4*)p;
    const float4 b = *(const float4*)(p + 4);
    r.v[0] = a.x; r.v[1] = a.y; r.v[2] = a.z; r.v[3] = a.w;
    r.v[4] = b.x; r.v[5] = b.y; r.v[6] = b.z; r.v[7] = b.w;
    return r;
}

// prep 1: out init + weight transpose -> bf16 [n][k]
__global__ void cfr_prep_w(const float* __restrict__ w_s1, const float* __restrict__ w_s2,
                           const float* __restrict__ w_f1, const float* __restrict__ w_f2,
                           const float* __restrict__ w_o1,
                           const float* __restrict__ fb, float* __restrict__ out,
                           unsigned short* __restrict__ wt) {
    int i = blockIdx.x * 256 + threadIdx.x;
    if (i < NPROBE) out[i] = fb[0];
    if (i < WT_TOT) {
        float v;
        if (i < WS2_O)      { int n = i / 384, k = i - n * 384;          v = w_s1[k * 128 + n]; }
        else if (i < WF1_O) { int j = i - WS2_O, n = j >> 7, k = j & 127; v = w_s2[k * 128 + n]; }
        else if (i < WF2_O) { int j = i - WF1_O, n = j >> 5, k = j & 31;  v = w_f1[k * 128 + n]; }
        else if (i < WO1_O) { int j = i - WF2_O, n = j >> 7, k = j & 127; v = w_f2[k * 128 + n]; }
        else                { int j = i - WO1_O, n = j >> 7, k = j & 127; v = w_o1[k * 64 + n]; }
        wt[i] = (unsigned short)f2bf(v);
    }
}

// prep 2: per-atom P = [S|n]@w_s1[0:256] + b_s1 and Q_d = V_d@w_s1[256:384], bf16.
// One block = 64 atoms. LDS 81920 B (XOR-swizzled, no pad) -> 2 blocks/CU.
__global__ __launch_bounds__(256, 2) void cfr_prep_pq(
    const float* __restrict__ S, const float* __restrict__ V,
    const float* __restrict__ b_s1,
    const unsigned short* __restrict__ wt, unsigned short* __restrict__ pq)
{
    __shared__ __align__(16) unsigned short bufH[64 * 256];   // [S|n], swizzled rows of 512 B
    __shared__ __align__(16) unsigned short bufV[192 * 128];  // rows (d*64 + a_local), 256 B

    const int t    = threadIdx.x;
    const int a0   = blockIdx.x * 64;
    const int wave = t >> 6;
    const int lane = t & 63;
    const int q    = lane >> 4;
    const int c16  = lane & 15;

    // stage
#pragma unroll
    for (int it = 0; it < 4; ++it) {
        int idx = it * 256 + t;
        int al = idx >> 4, f8 = (idx & 15) * 8;
        int a = a0 + al;
        ushort8 sS, sN, s0, s1, s2;
        if (a < N_ATOMS) {
            F8 s  = ld8(S + a * 128 + f8);
            F8 v0 = ld8(V + a * 384 + f8);
            F8 v1 = ld8(V + a * 384 + 128 + f8);
            F8 v2 = ld8(V + a * 384 + 256 + f8);
#pragma unroll
            for (int j = 0; j < 8; ++j) {
                sS[j] = (unsigned short)f2bf(s.v[j]);
                sN[j] = (unsigned short)f2bf(sqrtf(v0.v[j]*v0.v[j] + v1.v[j]*v1.v[j] + v2.v[j]*v2.v[j] + 1e-8f));
                s0[j] = (unsigned short)f2bf(v0.v[j]);
                s1[j] = (unsigned short)f2bf(v1.v[j]);
                s2[j] = (unsigned short)f2bf(v2.v[j]);
            }
        } else {
#pragma unroll
            for (int j = 0; j < 8; ++j) { sS[j]=0; sN[j]=0; s0[j]=0; s1[j]=0; s2[j]=0; }
        }
        const unsigned swH = (unsigned)((al & 7) << 4);
        char* hrow  = (char*)bufH + al * 512;
        char* vbase = (char*)bufV;
        *(ushort8*)(hrow + ((f8 * 2) ^ swH))         = sS;
        *(ushort8*)(hrow + ((256 + f8 * 2) ^ swH))   = sN;
        *(ushort8*)(vbase + al * 256         + ((f8 * 2) ^ swH)) = s0;
        *(ushort8*)(vbase + (64 + al) * 256  + ((f8 * 2) ^ swH)) = s1;
        *(ushort8*)(vbase + (128 + al) * 256 + ((f8 * 2) ^ swH)) = s2;
    }
    __syncthreads();

    const floatx4 zero4 = {0.f, 0.f, 0.f, 0.f};
    const unsigned swr = (unsigned)((c16 & 7) << 4);
    float bs1c[2];
#pragma unroll
    for (int ni = 0; ni < 2; ++ni) bs1c[ni] = b_s1[wave * 32 + ni * 16 + c16];

    // P = [S|n] @ w_s1[0:256]
    {
        floatx4 pacc[4][2];
#pragma unroll
        for (int mi = 0; mi < 4; ++mi) { pacc[mi][0] = zero4; pacc[mi][1] = zero4; }
#pragma unroll
        for (int kk = 0; kk < 8; ++kk) {
            short8 bfr[2], af[4];
#pragma unroll
            for (int ni = 0; ni < 2; ++ni) {
                int n = wave * 32 + ni * 16 + c16;
                bfr[ni] = *(const short8*)&wt[WS1_O + n * 384 + kk * 32 + q * 8];
            }
#pragma unroll
            for (int mi = 0; mi < 4; ++mi) {
                int row = mi * 16 + c16;
                af[mi] = *(const short8*)((const char*)bufH + row * 512 + ((unsigned)(kk * 64 + q * 16) ^ swr));
            }
#pragma unroll
            for (int mi = 0; mi < 4; ++mi)
#pragma unroll
                for (int ni = 0; ni < 2; ++ni)
                    pacc[mi][ni] = MFMA16(af[mi], bfr[ni], pacc[mi][ni]);
        }
#pragma unroll
        for (int mi = 0; mi < 4; ++mi)
#pragma unroll
            for (int r = 0; r < 4; ++r) {
                int a = a0 + mi * 16 + q * 4 + r;
                if (a < N_ATOMS)
#pragma unroll
                    for (int ni = 0; ni < 2; ++ni) {
                        int col = wave * 32 + ni * 16 + c16;
                        pq[a * 512 + col] = (unsigned short)f2bf(pacc[mi][ni][r] + bs1c[ni]);
                    }
            }
    }

    // Q_d = V_d @ w_s1[256:384] (B frags hoisted)
    short8 bq[4][2];
#pragma unroll
    for (int kk = 0; kk < 4; ++kk)
#pragma unroll
        for (int ni = 0; ni < 2; ++ni) {
            int n = wave * 32 + ni * 16 + c16;
            bq[kk][ni] = *(const short8*)&wt[WS1_O + n * 384 + 256 + kk * 32 + q * 8];
        }
#pragma unroll
    for (int d = 0; d < 3; ++d) {
        floatx4 qacc[4][2];
#pragma unroll
        for (int mi = 0; mi < 4; ++mi) { qacc[mi][0] = zero4; qacc[mi][1] = zero4; }
#pragma unroll
        for (int kk = 0; kk < 4; ++kk) {
            short8 af[4];
#pragma unroll
            for (int mi = 0; mi < 4; ++mi) {
                int row = d * 64 + mi * 16 + c16;
                af[mi] = *(const short8*)((const char*)bufV + row * 256 + ((unsigned)(kk * 64 + q * 16) ^ swr));
            }
#pragma unroll
            for (int mi = 0; mi < 4; ++mi)
#pragma unroll
                for (int ni = 0; ni < 2; ++ni)
                    qacc[mi][ni] = MFMA16(af[mi], bq[kk][ni], qacc[mi][ni]);
        }
#pragma unroll
        for (int mi = 0; mi < 4; ++mi)
#pragma unroll
            for (int r = 0; r < 4; ++r) {
                int a = a0 + mi * 16 + q * 4 + r;
                if (a < N_ATOMS)
#pragma unroll
                    for (int ni = 0; ni < 2; ++ni) {
                        int col = wave * 32 + ni * 16 + c16;
                        pq[a * 512 + (1 + d) * 128 + col] = (unsigned short)f2bf(qacc[mi][ni][r]);
                    }
            }
    }
}

// launch_bounds(256,4): the (256,5) variant capped the allocator and spilled
// (WRITE_SIZE 8MB -> 306MB scratch traffic). With ~60-70 VGPR and 32KB LDS the
// HW can still co-schedule 5 blocks/CU on its own.
__global__ __launch_bounds__(256, 4) void cfr_main(
    const float* __restrict__ diff,
    const int* __restrict__ atom_idx, const int* __restrict__ probe_idx,
    const unsigned short* __restrict__ wt, const unsigned short* __restrict__ pq,
    const float* __restrict__ g_ln, const float* __restrict__ b_ln,
    const float* __restrict__ b_s2, const float* __restrict__ b_f1,
    const float* __restrict__ b_f2, const float* __restrict__ b_o1,
    const float* __restrict__ w_o2, const float* __restrict__ b_o2,
    float* __restrict__ out)
{
    __shared__ __align__(16) unsigned short LDSu[LDS_SH];

    const int t    = threadIdx.x;
    const int e0   = blockIdx.x * EPB;
    const int wave = t >> 6;
    const int lane = t & 63;
    const int q    = lane >> 4;
    const int c16  = lane & 15;
    const floatx4 zero4 = {0.f, 0.f, 0.f, 0.f};

    // ---------- phase 1: U = P + r.Q -> LN -> SiLU -> A2 ; EPI ----------
    {
        const int el = t >> 2;             // local edge 0..63
        const int cc = t & 3;              // 32-col chunk id
        const int eg = e0 + el;
        const int a  = atom_idx[eg];
        float dx = diff[eg * 3 + 0], dy = diff[eg * 3 + 1], dz = diff[eg * 3 + 2];
        float sq   = dx * dx + dy * dy + dz * dz;
        float dist = sqrtf(sq);
        float rinv = rsqrtf(sq + 1e-8f);
        float rx = dx * rinv, ry = dy * rinv, rz = dz * rinv;
        float rv[3] = {rx, ry, rz};

        const uint4* pqr = (const uint4*)(pq + (size_t)a * 512) + cc * 4;
        floatx2 u2[16];
#pragma unroll
        for (int g = 0; g < 4; ++g) {          // P
            uint4 w = pqr[g];
            u2[g * 4 + 0] = bfpair(w.x);
            u2[g * 4 + 1] = bfpair(w.y);
            u2[g * 4 + 2] = bfpair(w.z);
            u2[g * 4 + 3] = bfpair(w.w);
        }
#pragma unroll
        for (int d = 0; d < 3; ++d) {          // + r_d * Q_d
            floatx2 rr2; rr2.x = rv[d]; rr2.y = rv[d];
#pragma unroll
            for (int g = 0; g < 4; ++g) {
                uint4 w = pqr[16 * (d + 1) + g];
                u2[g * 4 + 0] = fma2(bfpair(w.x), rr2, u2[g * 4 + 0]);
                u2[g * 4 + 1] = fma2(bfpair(w.y), rr2, u2[g * 4 + 1]);
                u2[g * 4 + 2] = fma2(bfpair(w.z), rr2, u2[g * 4 + 2]);
                u2[g * 4 + 3] = fma2(bfpair(w.w), rr2, u2[g * 4 + 3]);
            }
        }
        // LayerNorm stats: quad-local (threads t^1, t^2 share this edge)
        floatx2 sv2 = {0.f, 0.f}, qv2 = {0.f, 0.f};
#pragma unroll
        for (int p = 0; p < 16; ++p) {
            sv2 += u2[p];
            qv2 = fma2(u2[p], u2[p], qv2);
        }
        float s  = sv2.x + sv2.y;
        float s2 = qv2.x + qv2.y;
        s  += __shfl_xor(s, 1);  s  += __shfl_xor(s, 2);
        s2 += __shfl_xor(s2, 1); s2 += __shfl_xor(s2, 2);
        float mu = s * (1.f / 128.f);
        float rstd = rsqrtf(s2 * (1.f / 128.f) - mu * mu + 1e-5f);
        floatx2 rstd2; rstd2.x = rstd; rstd2.y = rstd;
        float nmr = -mu * rstd;
        floatx2 nm2; nm2.x = nmr; nm2.y = nmr;
        // LN apply + SiLU -> bf16 pack
        const int c0 = cc * 32;
        const float4* gp = (const float4*)(g_ln + c0);
        const float4* bp = (const float4*)(b_ln + c0);
        unsigned pko[16];
#pragma unroll
        for (int g4 = 0; g4 < 8; ++g4) {
            float4 gg = gp[g4], bb = bp[g4];
            floatx2 g0; g0.x = gg.x; g0.y = gg.y;
            floatx2 g1; g1.x = gg.z; g1.y = gg.w;
            floatx2 b0; b0.x = bb.x; b0.y = bb.y;
            floatx2 b1; b1.x = bb.z; b1.y = bb.w;
            floatx2 t0 = fma2(u2[g4 * 2 + 0], rstd2, nm2);
            floatx2 t1 = fma2(u2[g4 * 2 + 1], rstd2, nm2);
            floatx2 y0 = fma2(t0, g0, b0);
            floatx2 y1 = fma2(t1, g1, b1);
            pko[g4 * 2 + 0] = pk2(silu_f(y0.x), silu_f(y0.y));
            pko[g4 * 2 + 1] = pk2(silu_f(y1.x), silu_f(y1.y));
        }
        const unsigned sw = (unsigned)((el & 7) << 4);
        char* a2b = (char*)LDSu + el * 256;
        *(uint4*)(a2b + (((unsigned)(cc * 64) +  0u) ^ sw)) = make_uint4(pko[0],  pko[1],  pko[2],  pko[3]);
        *(uint4*)(a2b + (((unsigned)(cc * 64) + 16u) ^ sw)) = make_uint4(pko[4],  pko[5],  pko[6],  pko[7]);
        *(uint4*)(a2b + (((unsigned)(cc * 64) + 32u) ^ sw)) = make_uint4(pko[8],  pko[9],  pko[10], pko[11]);
        *(uint4*)(a2b + (((unsigned)(cc * 64) + 48u) ^ sw)) = make_uint4(pko[12], pko[13], pko[14], pko[15]);
        // EPI: 8 RBF cols per thread; v_sin takes revolutions: arg = dist*n/(2*CUTOFF*2) = dist*n*0.125
        float inv = __builtin_amdgcn_rcpf(dist);
        float d8  = dist * 0.125f;
        float nb  = (float)(cc * 8 + 1);
        float svv[8];
#pragma unroll
        for (int j = 0; j < 8; ++j)
            svv[j] = __builtin_amdgcn_sinf(d8 * (nb + (float)j)) * inv;
        *(uint4*)((char*)LDSu + F1_O * 2 + el * 80 + cc * 16) =
            make_uint4(pk2(svv[0], svv[1]), pk2(svv[2], svv[3]), pk2(svv[4], svv[5]), pk2(svv[6], svv[7]));
    }
    __syncthreads();   // A2 + EPI ready

    // ---------- mmf1: F1 = EPI[64x32] @ w_f1 -> silu -> F1A (overlays EPI after barrier) ----------
    {
        short8 ae[4], be[2];
#pragma unroll
        for (int mi = 0; mi < 4; ++mi)
            ae[mi] = *(const short8*)((const char*)LDSu + F1_O * 2 + (mi * 16 + c16) * 80 + q * 16);
#pragma unroll
        for (int ni = 0; ni < 2; ++ni) {
            int n = wave * 32 + ni * 16 + c16;
            be[ni] = *(const short8*)&wt[WF1_O + n * 32 + q * 8];
        }
        __syncthreads();   // all EPI reads complete before F1A overlay writes
        floatx4 facc[4][2];
#pragma unroll
        for (int mi = 0; mi < 4; ++mi)
#pragma unroll
            for (int ni = 0; ni < 2; ++ni)
                facc[mi][ni] = MFMA16(ae[mi], be[ni], zero4);
        float bf1c[2];
#pragma unroll
        for (int ni = 0; ni < 2; ++ni) bf1c[ni] = b_f1[wave * 32 + ni * 16 + c16];
#pragma unroll
        for (int mi = 0; mi < 4; ++mi)
#pragma unroll
            for (int r = 0; r < 4; ++r) {
                int row = mi * 16 + q * 4 + r;
#pragma unroll
                for (int ni = 0; ni < 2; ++ni) {
                    int col = wave * 32 + ni * 16 + c16;
                    float v = facc[mi][ni][r] + bf1c[ni];
                    LDSu[F1_O + row * 128 + (col ^ ((row & 7) << 3))] =
                        (unsigned short)(__builtin_bit_cast(unsigned, silu_f(v)) >> 16);
                }
            }
    }
    __syncthreads();   // F1A ready

    // ---------- mm2: S = A2 @ w_s2 ; mmf2: W = F1A @ w_f2 ; G = S.W -> A2 region ----------
    {
        floatx4 sacc[4][2], wacc[4][2];
#pragma unroll
        for (int mi = 0; mi < 4; ++mi)
#pragma unroll
            for (int ni = 0; ni < 2; ++ni) { sacc[mi][ni] = zero4; wacc[mi][ni] = zero4; }
        const int swr = (c16 & 7) << 3;
#pragma unroll
        for (int kk = 0; kk < 4; ++kk) {
            short8 a2f[4], f1f[4], b2[2], bw[2];
#pragma unroll
            for (int ni = 0; ni < 2; ++ni) {
                int n = wave * 32 + ni * 16 + c16;
                b2[ni] = *(const short8*)&wt[WS2_O + n * 128 + kk * 32 + q * 8];
                bw[ni] = *(const short8*)&wt[WF2_O + n * 128 + kk * 32 + q * 8];
            }
#pragma unroll
            for (int mi = 0; mi < 4; ++mi) {
                int rr = mi * 16 + c16;
                int colsh = (kk * 32 + q * 8) ^ swr;
                a2f[mi] = *(const short8*)&LDSu[A2_O + rr * 128 + colsh];
                f1f[mi] = *(const short8*)&LDSu[F1_O + rr * 128 + colsh];
            }
#pragma unroll
            for (int mi = 0; mi < 4; ++mi)
#pragma unroll
                for (int ni = 0; ni < 2; ++ni) {
                    sacc[mi][ni] = MFMA16(a2f[mi], b2[ni], sacc[mi][ni]);
                    wacc[mi][ni] = MFMA16(f1f[mi], bw[ni], wacc[mi][ni]);
                }
        }
        __syncthreads();   // all reads of A2/F1A complete
        float bs2c[2], bf2c[2];
#pragma unroll
        for (int ni = 0; ni < 2; ++ni) {
            int col = wave * 32 + ni * 16 + c16;
            bs2c[ni] = b_s2[col]; bf2c[ni] = b_f2[col];
        }
#pragma unroll
        for (int mi = 0; mi < 4; ++mi)
#pragma unroll
            for (int r = 0; r < 4; ++r) {
                int row = mi * 16 + q * 4 + r;
#pragma unroll
                for (int ni = 0; ni < 2; ++ni) {
                    int col = wave * 32 + ni * 16 + c16;
                    float g = (sacc[mi][ni][r] + bs2c[ni]) * (wacc[mi][ni][r] + bf2c[ni]);
                    LDSu[A2_O + row * 128 + (col ^ ((row & 7) << 3))] =
                        (unsigned short)(__builtin_bit_cast(unsigned, g) >> 16);
                }
            }
    }
    __syncthreads();   // G ready

    // ---------- head: O1 = G @ w_o1 ; m = silu(O1) @ w_o2 ----------
    {
        const int n2 = wave * 16 + c16;
        const int swr = (c16 & 7) << 3;
        floatx4 oacc[4];
#pragma unroll
        for (int mi = 0; mi < 4; ++mi) oacc[mi] = zero4;
#pragma unroll
        for (int kk = 0; kk < 4; ++kk) {
            short8 bfr = *(const short8*)&wt[WO1_O + n2 * 128 + kk * 32 + q * 8];
#pragma unroll
            for (int mi = 0; mi < 4; ++mi) {
                int rr = mi * 16 + c16;
                short8 af = *(const short8*)&LDSu[A2_O + rr * 128 + ((kk * 32 + q * 8) ^ swr)];
                oacc[mi] = MFMA16(af, bfr, oacc[mi]);
            }
        }
        float bo1c = b_o1[n2], wo2c = w_o2[n2];
        float* mpart = (float*)&LDSu[F1_O];   // overlays F1A (dead after mm2)
#pragma unroll
        for (int mi = 0; mi < 4; ++mi)
#pragma unroll
            for (int r = 0; r < 4; ++r) {
                float s = silu_f(oacc[mi][r] + bo1c) * wo2c;
#pragma unroll
                for (int d = 1; d < 16; d <<= 1) s += __shfl_xor(s, d, 64);
                if (c16 == 0) mpart[(mi * 16 + q * 4 + r) * 4 + wave] = s;
            }
    }
    __syncthreads();

    // ---------- envelope + scatter-add ----------
    if (t < EPB) {
        int eg = e0 + t;
        const float* mpart = (const float*)&LDSu[F1_O];
        float4 mp = *(const float4*)&mpart[t * 4];
        float m = mp.x + mp.y + mp.z + mp.w + b_o2[0];
        float dx = diff[eg * 3 + 0], dy = diff[eg * 3 + 1], dz = diff[eg * 3 + 2];
        float dist = sqrtf(dx * dx + dy * dy + dz * dz);
        float x  = dist * 0.25f;
        float x2 = x * x, x4 = x2 * x2;
        float x5 = x4 * x, x6 = x5 * x, x7 = x6 * x;
        float env = 1.0f - 21.0f * x5 + 35.0f * x6 - 15.0f * x7;
        env = (dist < 4.0f) ? env : 0.0f;
        float mw = m * env;
        if (mw != 0.f) unsafeAtomicAdd(&out[probe_idx[eg]], mw);
    }
}

extern "C" void kernel_launch(void* const* d_in, const int* in_sizes, int n_in,
                              void* d_out, int out_size, void* d_ws, size_t ws_size,
                              hipStream_t stream) {
    const float* diff    = (const float*)d_in[0];
    const float* S_JK    = (const float*)d_in[1];
    const float* V_JK    = (const float*)d_in[2];
    const int*   atom_i  = (const int*)d_in[3];
    const int*   probe_i = (const int*)d_in[4];
    const float* w_s1 = (const float*)d_in[6];
    const float* b_s1 = (const float*)d_in[7];
    const float* g_ln = (const float*)d_in[8];
    const float* b_ln = (const float*)d_in[9];
    const float* w_s2 = (const float*)d_in[10];
    const float* b_s2 = (const float*)d_in[11];
    const float* w_f1 = (const float*)d_in[12];
    const float* b_f1 = (const float*)d_in[13];
    const float* w_f2 = (const float*)d_in[14];
    const float* b_f2 = (const float*)d_in[15];
    const float* w_o1 = (const float*)d_in[16];
    const float* b_o1 = (const float*)d_in[17];
    const float* w_o2 = (const float*)d_in[18];
    const float* b_o2 = (const float*)d_in[19];
    const float* fbias = (const float*)d_in[20];
    float* out = (float*)d_out;

    unsigned short* wt = (unsigned short*)d_ws;
    unsigned short* pqp = wt + PQ_O;   // 20.5 MB

    cfr_prep_w<<<(NPROBE + 255) / 256, 256, 0, stream>>>(w_s1, w_s2, w_f1, w_f2, w_o1,
                                                         fbias, out, wt);
    cfr_prep_pq<<<(N_ATOMS + 63) / 64, 256, 0, stream>>>(S_JK, V_JK, b_s1, wt, pqp);
    cfr_main<<<E_TOTAL / EPB, 256, 0, stream>>>(diff, atom_i, probe_i, wt, pqp,
        g_ln, b_ln, b_s2, b_f1, b_f2, b_o1, w_o2, b_o2, out);
}

// Round 3
// 232.081 us; speedup vs baseline: 1.4296x; 1.1720x over previous
//
#include <hip/hip_runtime.h>

#define EPB     64
#define E_TOTAL 262144
#define NPROBE  100000
#define N_ATOMS 20000

// LDS layout (main), unsigned short indices; total 39,936 B (proven round-0 layout)
#define ASTR   136           // A2/F1A row stride: 272 B = 16 B * 17 -> 2-way (free) banks
#define A2_O   0             // A2 / G region [0, 8704)
#define F1_O   8704          // F1A region    [8704, 17408)
#define EPI_O  17408         // EPI 64 x 40 shorts; overlaid by mpart floats in head phase
#define LDS_SH 19968         // 39,936 B -> 4 blocks/CU

// workspace layout (shorts)
#define WS1_O  0             // w_s1^T bf16: 128 x 384 ([n][k])
#define WS2_O  49152         // 128 x 128
#define WF1_O  65536         // 128 x 32
#define WF2_O  69632         // 128 x 128
#define WO1_O  86016         // 64 x 128
#define WT_TOT 94208
#define PQ_O   WT_TOT        // PQ[a][512] bf16: [P | Q0 | Q1 | Q2], 20.5 MB

typedef __attribute__((ext_vector_type(8))) short          short8;
typedef __attribute__((ext_vector_type(8))) unsigned short ushort8;
typedef __attribute__((ext_vector_type(4))) float          floatx4;

#define MFMA16(a, b, c) __builtin_amdgcn_mfma_f32_16x16x32_bf16((a), (b), (c), 0, 0, 0)

__device__ __forceinline__ short f2bf(float x) {            // RNE (prep only)
    unsigned u = __builtin_bit_cast(unsigned, x);
    u = (u + 0x7FFFu + ((u >> 16) & 1u)) >> 16;
    return (short)(unsigned short)u;
}
__device__ __forceinline__ unsigned pk2(float lo, float hi) {   // {bf16(hi)|bf16(lo)} trunc
    return __builtin_amdgcn_perm(__builtin_bit_cast(unsigned, hi),
                                 __builtin_bit_cast(unsigned, lo), 0x07060302u);
}
__device__ __forceinline__ float bf2f(unsigned short u) {
    return __builtin_bit_cast(float, ((unsigned)u) << 16);
}
// silu via raw v_rcp (1 ulp) instead of IEEE f32 divide (~10-instr div sequence)
__device__ __forceinline__ float silu_f(float x) {
    return x * __builtin_amdgcn_rcpf(1.0f + __expf(-x));
}

struct F8 { float v[8]; };
__device__ __forceinline__ F8 ld8(const float* __restrict__ p) {
    F8 r;
    const float4 a = *(const float4*)p;
    const float4 b = *(const float4*)(p + 4);
    r.v[0] = a.x; r.v[1] = a.y; r.v[2] = a.z; r.v[3] = a.w;
    r.v[4] = b.x; r.v[5] = b.y; r.v[6] = b.z; r.v[7] = b.w;
    return r;
}

// prep 1: out init + weight transpose -> bf16 [n][k]
__global__ void cfr_prep_w(const float* __restrict__ w_s1, const float* __restrict__ w_s2,
                           const float* __restrict__ w_f1, const float* __restrict__ w_f2,
                           const float* __restrict__ w_o1,
                           const float* __restrict__ fb, float* __restrict__ out,
                           unsigned short* __restrict__ wt) {
    int i = blockIdx.x * 256 + threadIdx.x;
    if (i < NPROBE) out[i] = fb[0];
    if (i < WT_TOT) {
        float v;
        if (i < WS2_O)      { int n = i / 384, k = i - n * 384;          v = w_s1[k * 128 + n]; }
        else if (i < WF1_O) { int j = i - WS2_O, n = j >> 7, k = j & 127; v = w_s2[k * 128 + n]; }
        else if (i < WF2_O) { int j = i - WF1_O, n = j >> 5, k = j & 31;  v = w_f1[k * 128 + n]; }
        else if (i < WO1_O) { int j = i - WF2_O, n = j >> 7, k = j & 127; v = w_f2[k * 128 + n]; }
        else                { int j = i - WO1_O, n = j >> 7, k = j & 127; v = w_o1[k * 64 + n]; }
        wt[i] = (unsigned short)f2bf(v);
    }
}

// prep 2: per-atom P = [S|n]@w_s1[0:256] + b_s1 and Q_d = V_d@w_s1[256:384], bf16.
// One block = 64 atoms. LDS 81920 B (XOR-swizzled, no pad) -> 2 blocks/CU. (validated round 2)
__global__ __launch_bounds__(256, 2) void cfr_prep_pq(
    const float* __restrict__ S, const float* __restrict__ V,
    const float* __restrict__ b_s1,
    const unsigned short* __restrict__ wt, unsigned short* __restrict__ pq)
{
    __shared__ __align__(16) unsigned short bufH[64 * 256];   // [S|n], swizzled rows of 512 B
    __shared__ __align__(16) unsigned short bufV[192 * 128];  // rows (d*64 + a_local), 256 B

    const int t    = threadIdx.x;
    const int a0   = blockIdx.x * 64;
    const int wave = t >> 6;
    const int lane = t & 63;
    const int q    = lane >> 4;
    const int c16  = lane & 15;

    // stage
#pragma unroll
    for (int it = 0; it < 4; ++it) {
        int idx = it * 256 + t;
        int al = idx >> 4, f8 = (idx & 15) * 8;
        int a = a0 + al;
        ushort8 sS, sN, s0, s1, s2;
        if (a < N_ATOMS) {
            F8 s  = ld8(S + a * 128 + f8);
            F8 v0 = ld8(V + a * 384 + f8);
            F8 v1 = ld8(V + a * 384 + 128 + f8);
            F8 v2 = ld8(V + a * 384 + 256 + f8);
#pragma unroll
            for (int j = 0; j < 8; ++j) {
                sS[j] = (unsigned short)f2bf(s.v[j]);
                sN[j] = (unsigned short)f2bf(sqrtf(v0.v[j]*v0.v[j] + v1.v[j]*v1.v[j] + v2.v[j]*v2.v[j] + 1e-8f));
                s0[j] = (unsigned short)f2bf(v0.v[j]);
                s1[j] = (unsigned short)f2bf(v1.v[j]);
                s2[j] = (unsigned short)f2bf(v2.v[j]);
            }
        } else {
#pragma unroll
            for (int j = 0; j < 8; ++j) { sS[j]=0; sN[j]=0; s0[j]=0; s1[j]=0; s2[j]=0; }
        }
        const unsigned swH = (unsigned)((al & 7) << 4);
        char* hrow  = (char*)bufH + al * 512;
        char* vbase = (char*)bufV;
        *(ushort8*)(hrow + ((f8 * 2) ^ swH))         = sS;
        *(ushort8*)(hrow + ((256 + f8 * 2) ^ swH))   = sN;
        *(ushort8*)(vbase + al * 256         + ((f8 * 2) ^ swH)) = s0;
        *(ushort8*)(vbase + (64 + al) * 256  + ((f8 * 2) ^ swH)) = s1;
        *(ushort8*)(vbase + (128 + al) * 256 + ((f8 * 2) ^ swH)) = s2;
    }
    __syncthreads();

    const floatx4 zero4 = {0.f, 0.f, 0.f, 0.f};
    const unsigned swr = (unsigned)((c16 & 7) << 4);
    float bs1c[2];
#pragma unroll
    for (int ni = 0; ni < 2; ++ni) bs1c[ni] = b_s1[wave * 32 + ni * 16 + c16];

    // P = [S|n] @ w_s1[0:256]
    {
        floatx4 pacc[4][2];
#pragma unroll
        for (int mi = 0; mi < 4; ++mi) { pacc[mi][0] = zero4; pacc[mi][1] = zero4; }
#pragma unroll
        for (int kk = 0; kk < 8; ++kk) {
            short8 bfr[2], af[4];
#pragma unroll
            for (int ni = 0; ni < 2; ++ni) {
                int n = wave * 32 + ni * 16 + c16;
                bfr[ni] = *(const short8*)&wt[WS1_O + n * 384 + kk * 32 + q * 8];
            }
#pragma unroll
            for (int mi = 0; mi < 4; ++mi) {
                int row = mi * 16 + c16;
                af[mi] = *(const short8*)((const char*)bufH + row * 512 + ((unsigned)(kk * 64 + q * 16) ^ swr));
            }
#pragma unroll
            for (int mi = 0; mi < 4; ++mi)
#pragma unroll
                for (int ni = 0; ni < 2; ++ni)
                    pacc[mi][ni] = MFMA16(af[mi], bfr[ni], pacc[mi][ni]);
        }
#pragma unroll
        for (int mi = 0; mi < 4; ++mi)
#pragma unroll
            for (int r = 0; r < 4; ++r) {
                int a = a0 + mi * 16 + q * 4 + r;
                if (a < N_ATOMS)
#pragma unroll
                    for (int ni = 0; ni < 2; ++ni) {
                        int col = wave * 32 + ni * 16 + c16;
                        pq[a * 512 + col] = (unsigned short)f2bf(pacc[mi][ni][r] + bs1c[ni]);
                    }
            }
    }

    // Q_d = V_d @ w_s1[256:384] (B frags hoisted)
    short8 bq[4][2];
#pragma unroll
    for (int kk = 0; kk < 4; ++kk)
#pragma unroll
        for (int ni = 0; ni < 2; ++ni) {
            int n = wave * 32 + ni * 16 + c16;
            bq[kk][ni] = *(const short8*)&wt[WS1_O + n * 384 + 256 + kk * 32 + q * 8];
        }
#pragma unroll
    for (int d = 0; d < 3; ++d) {
        floatx4 qacc[4][2];
#pragma unroll
        for (int mi = 0; mi < 4; ++mi) { qacc[mi][0] = zero4; qacc[mi][1] = zero4; }
#pragma unroll
        for (int kk = 0; kk < 4; ++kk) {
            short8 af[4];
#pragma unroll
            for (int mi = 0; mi < 4; ++mi) {
                int row = d * 64 + mi * 16 + c16;
                af[mi] = *(const short8*)((const char*)bufV + row * 256 + ((unsigned)(kk * 64 + q * 16) ^ swr));
            }
#pragma unroll
            for (int mi = 0; mi < 4; ++mi)
#pragma unroll
                for (int ni = 0; ni < 2; ++ni)
                    qacc[mi][ni] = MFMA16(af[mi], bq[kk][ni], qacc[mi][ni]);
        }
#pragma unroll
        for (int mi = 0; mi < 4; ++mi)
#pragma unroll
            for (int r = 0; r < 4; ++r) {
                int a = a0 + mi * 16 + q * 4 + r;
                if (a < N_ATOMS)
#pragma unroll
                    for (int ni = 0; ni < 2; ++ni) {
                        int col = wave * 32 + ni * 16 + c16;
                        pq[a * 512 + (1 + d) * 128 + col] = (unsigned short)f2bf(qacc[mi][ni][r]);
                    }
            }
    }
}

// cfr_main: round-0 proven body (scalar phase 1, ASTR=136 layout) + scalar
// transcendental substitutions only (rcp-silu, v_sin in revolutions, rcp(dist)).
__global__ __launch_bounds__(256, 4) void cfr_main(
    const float* __restrict__ diff,
    const int* __restrict__ atom_idx, const int* __restrict__ probe_idx,
    const unsigned short* __restrict__ wt, const unsigned short* __restrict__ pq,
    const float* __restrict__ g_ln, const float* __restrict__ b_ln,
    const float* __restrict__ b_s2, const float* __restrict__ b_f1,
    const float* __restrict__ b_f2, const float* __restrict__ b_o1,
    const float* __restrict__ w_o2, const float* __restrict__ b_o2,
    float* __restrict__ out)
{
    __shared__ __align__(16) unsigned short LDSu[LDS_SH];
    float* mpart = (float*)&LDSu[EPI_O];   // overlays EPI after mmf1

    const int t    = threadIdx.x;
    const int e0   = blockIdx.x * EPB;
    const int wave = t >> 6;
    const int lane = t & 63;
    const int q    = lane >> 4;
    const int c16  = lane & 15;
    const floatx4 zero4 = {0.f, 0.f, 0.f, 0.f};

    // ---------- phase 1: U = P + r.Q -> LN -> SiLU -> A2 ; EPI ----------
    {
        const int el = t >> 2;             // local edge 0..63
        const int c0 = (t & 3) * 32;       // this thread's 32-col chunk
        const int eg = e0 + el;
        const int a  = atom_idx[eg];
        float dx = diff[eg * 3 + 0], dy = diff[eg * 3 + 1], dz = diff[eg * 3 + 2];
        float sq   = dx * dx + dy * dy + dz * dz;
        float dist = sqrtf(sq);
        float rinv = rsqrtf(sq + 1e-8f);
        float rx = dx * rinv, ry = dy * rinv, rz = dz * rinv;

        const ushort8* pqr = (const ushort8*)(pq + a * 512 + c0);
        float u[32];
#pragma unroll
        for (int g = 0; g < 4; ++g) {
            ushort8 v = pqr[g];            // P
#pragma unroll
            for (int j = 0; j < 8; ++j) u[g * 8 + j] = bf2f(v[j]);
        }
#pragma unroll
        for (int g = 0; g < 4; ++g) {
            ushort8 v = pqr[16 + g];       // Q0 (offset 128 shorts = 16 ushort8)
#pragma unroll
            for (int j = 0; j < 8; ++j) u[g * 8 + j] = fmaf(bf2f(v[j]), rx, u[g * 8 + j]);
        }
#pragma unroll
        for (int g = 0; g < 4; ++g) {
            ushort8 v = pqr[32 + g];       // Q1
#pragma unroll
            for (int j = 0; j < 8; ++j) u[g * 8 + j] = fmaf(bf2f(v[j]), ry, u[g * 8 + j]);
        }
#pragma unroll
        for (int g = 0; g < 4; ++g) {
            ushort8 v = pqr[48 + g];       // Q2
#pragma unroll
            for (int j = 0; j < 8; ++j) u[g * 8 + j] = fmaf(bf2f(v[j]), rz, u[g * 8 + j]);
        }
        // LayerNorm stats: quad-local (threads t^1, t^2 share this edge)
        float s = 0.f, s2 = 0.f;
#pragma unroll
        for (int j = 0; j < 32; ++j) { s += u[j]; s2 = fmaf(u[j], u[j], s2); }
        s  += __shfl_xor(s, 1);  s  += __shfl_xor(s, 2);
        s2 += __shfl_xor(s2, 1); s2 += __shfl_xor(s2, 2);
        float mu = s * (1.f / 128.f);
        float rstd = rsqrtf(s2 * (1.f / 128.f) - mu * mu + 1e-5f);
        // LN apply + SiLU -> bf16 pack
        const float4* gp = (const float4*)(g_ln + c0);
        const float4* bp = (const float4*)(b_ln + c0);
        unsigned pko[16];
#pragma unroll
        for (int g4 = 0; g4 < 8; ++g4) {
            float4 gg = gp[g4], bb = bp[g4];
            float y0 = silu_f((u[g4 * 4 + 0] - mu) * rstd * gg.x + bb.x);
            float y1 = silu_f((u[g4 * 4 + 1] - mu) * rstd * gg.y + bb.y);
            float y2 = silu_f((u[g4 * 4 + 2] - mu) * rstd * gg.z + bb.z);
            float y3 = silu_f((u[g4 * 4 + 3] - mu) * rstd * gg.w + bb.w);
            pko[g4 * 2 + 0] = pk2(y0, y1);
            pko[g4 * 2 + 1] = pk2(y2, y3);
        }
        uint4* dst = (uint4*)&LDSu[A2_O + el * ASTR + c0];
        dst[0] = make_uint4(pko[0], pko[1], pko[2], pko[3]);
        dst[1] = make_uint4(pko[4], pko[5], pko[6], pko[7]);
        dst[2] = make_uint4(pko[8], pko[9], pko[10], pko[11]);
        dst[3] = make_uint4(pko[12], pko[13], pko[14], pko[15]);
        // EPI: 8 RBF cols per thread; v_sin takes revolutions: sin(d*n*pi/4) -> rev = d*n/8
        float inv = __builtin_amdgcn_rcpf(dist);
        float d8  = dist * 0.125f;
        float sv[8];
#pragma unroll
        for (int j = 0; j < 8; ++j) {
            float nf = (float)((t & 3) * 8 + j + 1);
            sv[j] = __builtin_amdgcn_sinf(d8 * nf) * inv;
        }
        *(uint4*)&LDSu[EPI_O + el * 40 + (t & 3) * 8] =
            make_uint4(pk2(sv[0], sv[1]), pk2(sv[2], sv[3]), pk2(sv[4], sv[5]), pk2(sv[6], sv[7]));
    }
    __syncthreads();   // A2 + EPI ready

    // ---------- mmf1: F1 = EPI[64x32] @ w_f1 -> silu -> F1A ----------
    {
        short8 ae[4], be[2];
#pragma unroll
        for (int mi = 0; mi < 4; ++mi)
            ae[mi] = *(const short8*)&LDSu[EPI_O + (mi * 16 + c16) * 40 + q * 8];
#pragma unroll
        for (int ni = 0; ni < 2; ++ni) {
            int n = wave * 32 + ni * 16 + c16;
            be[ni] = *(const short8*)&wt[WF1_O + n * 32 + q * 8];
        }
        floatx4 facc[4][2];
#pragma unroll
        for (int mi = 0; mi < 4; ++mi)
#pragma unroll
            for (int ni = 0; ni < 2; ++ni)
                facc[mi][ni] = MFMA16(ae[mi], be[ni], zero4);
        float bf1c[2];
#pragma unroll
        for (int ni = 0; ni < 2; ++ni) bf1c[ni] = b_f1[wave * 32 + ni * 16 + c16];
#pragma unroll
        for (int mi = 0; mi < 4; ++mi)
#pragma unroll
            for (int r = 0; r < 4; ++r) {
                int row = mi * 16 + q * 4 + r;
#pragma unroll
                for (int ni = 0; ni < 2; ++ni) {
                    float v = facc[mi][ni][r] + bf1c[ni];
                    LDSu[F1_O + row * ASTR + (wave * 32 + ni * 16 + c16)] =
                        (unsigned short)(__builtin_bit_cast(unsigned, silu_f(v)) >> 16);
                }
            }
    }
    __syncthreads();   // F1A ready (EPI now dead)

    // ---------- mm2: S = A2 @ w_s2 ; mmf2: W = F1A @ w_f2 ; G = S.W -> A2 region ----------
    {
        floatx4 sacc[4][2], wacc[4][2];
#pragma unroll
        for (int mi = 0; mi < 4; ++mi)
#pragma unroll
            for (int ni = 0; ni < 2; ++ni) { sacc[mi][ni] = zero4; wacc[mi][ni] = zero4; }
#pragma unroll
        for (int kk = 0; kk < 4; ++kk) {
            short8 a2f[4], f1f[4], b2[2], bw[2];
#pragma unroll
            for (int ni = 0; ni < 2; ++ni) {
                int n = wave * 32 + ni * 16 + c16;
                b2[ni] = *(const short8*)&wt[WS2_O + n * 128 + kk * 32 + q * 8];
                bw[ni] = *(const short8*)&wt[WF2_O + n * 128 + kk * 32 + q * 8];
            }
#pragma unroll
            for (int mi = 0; mi < 4; ++mi) {
                a2f[mi] = *(const short8*)&LDSu[A2_O + (mi * 16 + c16) * ASTR + kk * 32 + q * 8];
                f1f[mi] = *(const short8*)&LDSu[F1_O + (mi * 16 + c16) * ASTR + kk * 32 + q * 8];
            }
#pragma unroll
            for (int mi = 0; mi < 4; ++mi)
#pragma unroll
                for (int ni = 0; ni < 2; ++ni) {
                    sacc[mi][ni] = MFMA16(a2f[mi], b2[ni], sacc[mi][ni]);
                    wacc[mi][ni] = MFMA16(f1f[mi], bw[ni], wacc[mi][ni]);
                }
        }
        __syncthreads();   // all reads of A2/F1A complete
        float bs2c[2], bf2c[2];
#pragma unroll
        for (int ni = 0; ni < 2; ++ni) {
            int col = wave * 32 + ni * 16 + c16;
            bs2c[ni] = b_s2[col]; bf2c[ni] = b_f2[col];
        }
#pragma unroll
        for (int mi = 0; mi < 4; ++mi)
#pragma unroll
            for (int r = 0; r < 4; ++r) {
                int row = mi * 16 + q * 4 + r;
#pragma unroll
                for (int ni = 0; ni < 2; ++ni) {
                    float g = (sacc[mi][ni][r] + bs2c[ni]) * (wacc[mi][ni][r] + bf2c[ni]);
                    LDSu[A2_O + row * ASTR + (wave * 32 + ni * 16 + c16)] =
                        (unsigned short)(__builtin_bit_cast(unsigned, g) >> 16);
                }
            }
    }
    __syncthreads();   // G ready

    // ---------- head: O1 = G @ w_o1 ; m = silu(O1) @ w_o2 ----------
    {
        const int n2 = wave * 16 + c16;
        floatx4 oacc[4];
#pragma unroll
        for (int mi = 0; mi < 4; ++mi) oacc[mi] = zero4;
#pragma unroll
        for (int kk = 0; kk < 4; ++kk) {
            short8 bfr = *(const short8*)&wt[WO1_O + n2 * 128 + kk * 32 + q * 8];
#pragma unroll
            for (int mi = 0; mi < 4; ++mi) {
                short8 af = *(const short8*)&LDSu[A2_O + (mi * 16 + c16) * ASTR + kk * 32 + q * 8];
                oacc[mi] = MFMA16(af, bfr, oacc[mi]);
            }
        }
        float bo1c = b_o1[n2], wo2c = w_o2[n2];
#pragma unroll
        for (int mi = 0; mi < 4; ++mi)
#pragma unroll
            for (int r = 0; r < 4; ++r) {
                float s = silu_f(oacc[mi][r] + bo1c) * wo2c;
#pragma unroll
                for (int d = 1; d < 16; d <<= 1) s += __shfl_xor(s, d, 64);
                if (c16 == 0) mpart[(mi * 16 + q * 4 + r) * 4 + wave] = s;
            }
    }
    __syncthreads();

    // ---------- envelope + scatter-add ----------
    if (t < EPB) {
        int eg = e0 + t;
        float m = mpart[t * 4 + 0] + mpart[t * 4 + 1] + mpart[t * 4 + 2] + mpart[t * 4 + 3] + b_o2[0];
        float dx = diff[eg * 3 + 0], dy = diff[eg * 3 + 1], dz = diff[eg * 3 + 2];
        float dist = sqrtf(dx * dx + dy * dy + dz * dz);
        float x  = dist * 0.25f;
        float x2 = x * x, x4 = x2 * x2;
        float x5 = x4 * x, x6 = x5 * x, x7 = x6 * x;
        float env = 1.0f - 21.0f * x5 + 35.0f * x6 - 15.0f * x7;
        env = (dist < 4.0f) ? env : 0.0f;
        float mw = m * env;
        if (mw != 0.f) unsafeAtomicAdd(&out[probe_idx[eg]], mw);
    }
}

extern "C" void kernel_launch(void* const* d_in, const int* in_sizes, int n_in,
                              void* d_out, int out_size, void* d_ws, size_t ws_size,
                              hipStream_t stream) {
    const float* diff    = (const float*)d_in[0];
    const float* S_JK    = (const float*)d_in[1];
    const float* V_JK    = (const float*)d_in[2];
    const int*   atom_i  = (const int*)d_in[3];
    const int*   probe_i = (const int*)d_in[4];
    const float* w_s1 = (const float*)d_in[6];
    const float* b_s1 = (const float*)d_in[7];
    const float* g_ln = (const float*)d_in[8];
    const float* b_ln = (const float*)d_in[9];
    const float* w_s2 = (const float*)d_in[10];
    const float* b_s2 = (const float*)d_in[11];
    const float* w_f1 = (const float*)d_in[12];
    const float* b_f1 = (const float*)d_in[13];
    const float* w_f2 = (const float*)d_in[14];
    const float* b_f2 = (const float*)d_in[15];
    const float* w_o1 = (const float*)d_in[16];
    const float* b_o1 = (const float*)d_in[17];
    const float* w_o2 = (const float*)d_in[18];
    const float* b_o2 = (const float*)d_in[19];
    const float* fbias = (const float*)d_in[20];
    float* out = (float*)d_out;

    unsigned short* wt = (unsigned short*)d_ws;
    unsigned short* pqp = wt + PQ_O;   // 20.5 MB

    cfr_prep_w<<<(NPROBE + 255) / 256, 256, 0, stream>>>(w_s1, w_s2, w_f1, w_f2, w_o1,
                                                         fbias, out, wt);
    cfr_prep_pq<<<(N_ATOMS + 63) / 64, 256, 0, stream>>>(S_JK, V_JK, b_s1, wt, pqp);
    cfr_main<<<E_TOTAL / EPB, 256, 0, stream>>>(diff, atom_i, probe_i, wt, pqp,
        g_ln, b_ln, b_s2, b_f1, b_f2, b_o1, w_o2, b_o2, out);
}